// Round 15
// baseline (1547.023 us; speedup 1.0000x reference)
//
#include <hip/hip_runtime.h>
#include <hip/hip_fp16.h>

// GATConv: N=50000, E=1600000, DIM_IN=256, HEADS=4, DIM_OUT=32 (HC=128)
// R25: csr sort DELETED. Aggregation works directly on unsorted buckets:
//   k_bucket_agg = 1 block per (bucket, quarter): 64 nodes x 128ch f32 acc in
//   LDS (34.8KB -> 4 blk/CU, 100% occupancy); scans bucket's binned entries
//   (wave-uniform nl filter), LDS-atomic accumulate; epilogue self-loop +
//   divide + bias + coalesced store. Deletes csr kernel + srt/off/deg + 1
//   boundary. R23/R24 spin-fusion abandoned (launch_bounds-forced VGPR=32
//   spilled MFMA accumulators -> scratch traffic, +34MB writes).
//   Pipeline: D0 zero+wtrans; D1 bin||proj (R22); D2 bucket_agg.

#define DIN 256
#define HC 128
#define NH 4
#define NEG 0.2f
#define BCAP 12288
#define LOG2E 1.44269504f

typedef _Float16 half8 __attribute__((ext_vector_type(8)));
typedef _Float16 half2v __attribute__((ext_vector_type(2)));
typedef float f32x4 __attribute__((ext_vector_type(4)));

// ---------------- projection body (MFMA) + fused attention logits ----------------
// Per-sub-block sm layout (18432B): xs [64][40] halves @0; Wl [128][40] @5120;
//   ep [64][136] @0 (reused); attSL @17408, attDL @17920.
// tid = sub-block-local thread id (0..255).
// a_src/a_dst written PRE-SCALED by log2(e) for exp2f consumers.
__device__ __forceinline__ void proj_body(char* sm, int tid, const float* __restrict__ x,
                                          const _Float16* __restrict__ Wt,
                                          const float* __restrict__ attS,
                                          const float* __restrict__ attD,
                                          __half* __restrict__ xph,
                                          float* __restrict__ a_src,
                                          float* __restrict__ a_dst, int n, int node0) {
    _Float16* xs = (_Float16*)sm;
    _Float16* Wl = (_Float16*)(sm + 5120);
    _Float16* ep = (_Float16*)sm;
    float* attSL = (float*)(sm + 17408);
    float* attDL = (float*)(sm + 17920);

    const int wave = tid >> 6;
    const int lane = tid & 63;
    const int l15  = lane & 15;
    const int quad = lane >> 4;

    if (tid < 128) attSL[tid] = attS[tid];
    else           attDL[tid - 128] = attD[tid - 128];

    f32x4 acc[8];
#pragma unroll
    for (int ct = 0; ct < 8; ++ct) acc[ct] = (f32x4){0.f, 0.f, 0.f, 0.f};

    for (int kt = 0; kt < DIN; kt += 32) {
        __syncthreads();
#pragma unroll
        for (int r = 0; r < 4; ++r) {
            int idx = tid + r * 256;
            int row = idx >> 4;
            int kp  = idx & 15;
            int gn = node0 + row;
            float2 xv = make_float2(0.f, 0.f);
            if (gn < n) xv = *(const float2*)&x[(size_t)gn * DIN + kt + kp * 2];
            half2v p; p[0] = (_Float16)xv.x; p[1] = (_Float16)xv.y;
            *(half2v*)&xs[row * 40 + kp * 2] = p;
        }
#pragma unroll
        for (int r = 0; r < 2; ++r) {
            int id = tid + r * 256;
            int c = id >> 2;
            int q = id & 3;
            half8 wv = *(const half8*)&Wt[(size_t)c * 256 + kt + q * 8];
            *(half8*)&Wl[c * 40 + q * 8] = wv;
        }
        __syncthreads();
        half8 af = *(const half8*)&xs[(wave * 16 + l15) * 40 + quad * 8];
#pragma unroll
        for (int ct = 0; ct < 8; ++ct) {
            half8 bf = *(const half8*)&Wl[(ct * 16 + l15) * 40 + quad * 8];
            acc[ct] = __builtin_amdgcn_mfma_f32_16x16x32_f16(af, bf, acc[ct], 0, 0, 0);
        }
    }
    __syncthreads();
#pragma unroll
    for (int ct = 0; ct < 8; ++ct)
#pragma unroll
        for (int r = 0; r < 4; ++r) {
            int row = wave * 16 + quad * 4 + r;
            ep[row * 136 + ct * 16 + l15] = (_Float16)acc[ct][r];
        }
    __syncthreads();
    {
        int row = tid >> 2, ch = tid & 3;
        int node = node0 + row;
        if (node < n) {
            const uint4* s = (const uint4*)&ep[row * 136 + ch * 32];
            uint4* d = (uint4*)&xph[(size_t)node * HC + ch * 32];
            d[0] = s[0]; d[1] = s[1]; d[2] = s[2]; d[3] = s[3];
        }
    }
    {
        int nl = tid >> 2, h = tid & 3;
        int node = node0 + nl;
        if (node < n) {
            float ps = 0.f, pd = 0.f;
            const _Float16* er = &ep[nl * 136 + h * 32];
#pragma unroll
            for (int c = 0; c < 32; ++c) {
                float v = (float)er[c];
                ps += v * attSL[h * 32 + c];
                pd += v * attDL[h * 32 + c];
            }
            a_src[node * NH + h] = ps * LOG2E;
            a_dst[node * NH + h] = pd * LOG2E;
        }
    }
}

// ---------------- D0: zero gcur0 || wtrans ----------------
__global__ __launch_bounds__(256) void k_zero_wtrans(int* __restrict__ gz,
                                                     const float* __restrict__ W,
                                                     _Float16* __restrict__ Wt) {
    const int b = blockIdx.x;
    if (b < 2) {
        gz[b * 256 + threadIdx.x] = 0;
    } else {
        int i = (b - 2) * 256 + threadIdx.x;
        int k = i >> 7, c = i & 127;
        Wt[c * 256 + k] = (_Float16)W[i];
    }
}

// ---------------- D1: bin (fixed-capacity buckets, self-allocating) || proj ----------------
// blocks [0,ech): bin, 512t, 8 edges/thread.  blocks [ech,..): 2x proj sub-tiles.
__global__ __launch_bounds__(512) void k_bin_proj(const int* __restrict__ ei,
                                                  int* __restrict__ gcur0,
                                                  unsigned* __restrict__ binned,
                                                  const float* __restrict__ x,
                                                  const _Float16* __restrict__ Wt,
                                                  const float* __restrict__ attS,
                                                  const float* __restrict__ attD,
                                                  __half* __restrict__ xph,
                                                  float* __restrict__ a_src,
                                                  float* __restrict__ a_dst,
                                                  int e, int n, int ech) {
    __shared__ __attribute__((aligned(16))) char sm[36864];
    if ((int)blockIdx.x < ech) {
        int* h     = (int*)sm;
        int* rbase = (int*)(sm + 1024);
        const int tid = threadIdx.x;
        if (tid < 256) h[tid] = 0;
        __syncthreads();
        const int base = blockIdx.x * 4096;
        unsigned pk[8];
        int bk[8];
#pragma unroll
        for (int j = 0; j < 8; ++j) {
            int i = base + j * 512 + tid;
            bk[j] = -1;
            if (i < e) {
                int src = ei[i];
                int dst = ei[e + i];
                if ((unsigned)dst < (unsigned)n && (unsigned)src < (unsigned)n) {
                    bk[j] = dst >> 8;
                    pk[j] = ((unsigned)(dst & 255) << 16) | (unsigned)src;
                    atomicAdd(&h[bk[j]], 1);
                }
            }
        }
        __syncthreads();
        if (tid < 256) {
            if (h[tid]) rbase[tid] = atomicAdd(&gcur0[tid], h[tid]);
            h[tid] = 0;
        }
        __syncthreads();
#pragma unroll
        for (int j = 0; j < 8; ++j) {
            if (bk[j] >= 0) {
                int p = atomicAdd(&h[bk[j]], 1);
                int pib = rbase[bk[j]] + p;
                if (pib < BCAP) binned[(size_t)bk[j] * BCAP + pib] = pk[j];
            }
        }
    } else {
        const int sub = threadIdx.x >> 8;       // 0 or 1
        const int tid = threadIdx.x & 255;
        const int tile = ((int)blockIdx.x - ech) * 2 + sub;
        proj_body(sm + sub * 18432, tid, x, Wt, attS, attD, xph, a_src, a_dst, n, tile * 64);
    }
}

// ---------------- D2: bucket-resident aggregation (replaces csr + agg) ----------------
// Block = (bucket b, quarter q): owns nodes [b*256+q*64, +64). LDS f32 acc
// [64][128] + den[64][4] + a_dst cache. Scans the bucket's unsorted binned
// entries; nl is wave-uniform per edge -> uniform filter branch (skip 3/4).
// Gather: half2/lane (wave = 256B line of xph[src]); LDS atomics 2-way-bank
// aliased (free). Epilogue: self-loop + divide + bias + coalesced store.
__global__ __launch_bounds__(512) void k_bucket_agg(const unsigned* __restrict__ binned,
                                                    const int* __restrict__ gcnt,
                                                    const __half* __restrict__ xph,
                                                    const float* __restrict__ a_src,
                                                    const float* __restrict__ a_dst,
                                                    const float* __restrict__ bias,
                                                    float* __restrict__ out, int n) {
    __shared__ float acc[64 * 128];   // 32768 B
    __shared__ float den[64 * 4];     // 1024 B
    __shared__ float adl[64 * 4];     // 1024 B  (pre-scaled a_dst cache)
    const int b = blockIdx.x >> 2;
    const int q = blockIdx.x & 3;
    const int tid = threadIdx.x;
    const int nbase = b * 256 + q * 64;

    for (int i = tid; i < 64 * 128; i += 512) acc[i] = 0.f;
    if (tid < 256) {
        den[tid] = 0.f;
        int node = nbase + (tid >> 2);
        adl[tid] = (node < n) ? a_dst[node * 4 + (tid & 3)] : 0.f;
    }
    __syncthreads();

    const int cb = min(gcnt[b], BCAP);
    const int kb = b * BCAP;
    const int wave = tid >> 6;
    const int lane = tid & 63;
    const int h = lane >> 4;
    const unsigned ch2 = (unsigned)lane * 2u;

    const int ngrp = (cb + 3) >> 2;
    for (int gi = wave; gi < ngrp; gi += 8) {
        const int e0 = gi * 4;
        const uint4 e4 = *(const uint4*)&binned[kb + e0];
        const unsigned pv[4] = {e4.x, e4.y, e4.z, e4.w};
        const int m = cb - e0;                    // >= 1
        float asv[4];
        __half2 hv[4];
        bool val[4];
#pragma unroll
        for (int j = 0; j < 4; ++j) {
            int nl = (int)(pv[j] >> 16);
            val[j] = (j < m) && ((nl >> 6) == q);
            if (val[j]) {                          // wave-uniform branch
                unsigned src = pv[j] & 0xFFFFu;
                asv[j] = a_src[src * 4u + h];
                hv[j]  = ((const __half2*)xph)[src * 64u + lane];
            }
        }
#pragma unroll
        for (int j = 0; j < 4; ++j) {
            if (val[j]) {                          // wave-uniform branch
                int nloc = (int)((pv[j] >> 16) & 63);
                float t = asv[j] + adl[nloc * 4 + h];
                float s = exp2f(fmaxf(t, NEG * t));
                float2 vf = __half22float2(hv[j]);
                atomicAdd(&acc[nloc * 128 + ch2], s * vf.x);
                atomicAdd(&acc[nloc * 128 + ch2 + 1], s * vf.y);
                if ((lane & 15) == 0) atomicAdd(&den[nloc * 4 + h], s);
            }
        }
    }
    __syncthreads();

    // epilogue: 64 nodes x 32 groups-of-4ch = 2048 items
    for (int p = tid; p < 64 * 32; p += 512) {
        int nloc = p >> 5;
        int grp = p & 31;
        int node = nbase + nloc;
        if (node >= n) continue;
        int hh = grp >> 3;
        float t = a_src[node * 4 + hh] + adl[nloc * 4 + hh];
        float s = exp2f(fmaxf(t, NEG * t));       // self-loop score
        __half2 x0 = ((const __half2*)xph)[node * 64 + grp * 2];
        __half2 x1 = ((const __half2*)xph)[node * 64 + grp * 2 + 1];
        float2 f0 = __half22float2(x0), f1 = __half22float2(x1);
        float inv = 1.0f / (den[nloc * 4 + hh] + s);
        const float4 b4 = *(const float4*)&bias[grp * 4];
        float4 o;
        o.x = (acc[nloc * 128 + grp * 4 + 0] + s * f0.x) * inv + b4.x;
        o.y = (acc[nloc * 128 + grp * 4 + 1] + s * f0.y) * inv + b4.y;
        o.z = (acc[nloc * 128 + grp * 4 + 2] + s * f1.x) * inv + b4.z;
        o.w = (acc[nloc * 128 + grp * 4 + 3] + s * f1.y) * inv + b4.w;
        *(float4*)&out[(size_t)node * HC + grp * 4] = o;
    }
}

// ---------------- launch ----------------
extern "C" void kernel_launch(void* const* d_in, const int* in_sizes, int n_in,
                              void* d_out, int out_size, void* d_ws, size_t ws_size,
                              hipStream_t stream) {
    if (n_in < 6 || !d_out || !d_ws) return;
    const float* x    = (const float*)d_in[0];
    const int*   ei   = (const int*)d_in[1];
    const float* W    = (const float*)d_in[2];
    const float* attS = (const float*)d_in[3];
    const float* attD = (const float*)d_in[4];
    const float* bias = (const float*)d_in[5];
    float* out = (float*)d_out;

    const int N = in_sizes[0] / DIN;
    const int E = in_sizes[1] / 2;
    if (N <= 0 || E <= 0) return;
    const int NBUCK = (N + 255) >> 8;
    if (NBUCK > 256 || N > 65536) return;   // src fits 16 bits; 256-bucket scheme

    char* ws = (char*)d_ws;
    size_t off_b = 0;
    auto carve = [&](size_t bytes) {
        size_t p = off_b;
        off_b = (off_b + bytes + 255) & ~(size_t)255;
        return (void*)(ws + p);
    };
    __half*         xph    = (__half*)carve((size_t)N * HC * 2);
    _Float16*       Wt     = (_Float16*)carve((size_t)HC * DIN * 2);
    float*          a_src  = (float*)carve((size_t)N * NH * 4);
    float*          a_dst  = (float*)carve((size_t)N * NH * 4);
    int*            gz     = (int*)carve(512 * 4);        // gcur0[256] (+spare)
    unsigned*       binned = (unsigned*)carve((size_t)NBUCK * BCAP * 4);
    (void)out_size;
    if (off_b > ws_size) return;

    int* gcur0 = gz;

    const int ECH = (E + 4095) / 4096;      // bin blocks: 4096 edges each @512t
    const int PB  = (N + 63) / 64;          // 64-node proj tiles
    const int PBH = (PB + 1) / 2;           // proj blocks (2 tiles each)

    k_zero_wtrans<<<2 + 128, 256, 0, stream>>>(gz, W, Wt);
    k_bin_proj<<<ECH + PBH, 512, 0, stream>>>(ei, gcur0, binned, x, Wt, attS, attD,
                                              xph, a_src, a_dst, E, N, ECH);
    k_bucket_agg<<<NBUCK * 4, 512, 0, stream>>>(binned, gcur0, xph, a_src, a_dst,
                                                bias, out, N);
}

// Round 17
// 416.643 us; speedup vs baseline: 3.7131x; 3.7131x over previous
//
#include <hip/hip_runtime.h>
#include <hip/hip_fp16.h>

// GATConv: N=50000, E=1600000, DIM_IN=256, HEADS=4, DIM_OUT=32 (HC=128)
// R27 (= R26 resubmit; round 16 failed at container level, no counters; R23/R24
//   ran this exact flag protocol to completion -> design is HW-proven; R14->R15
//   precedent shows byte-identical resubmit after double container failure
//   passing cleanly):
//   R24 minus the launch_bounds(512,8) VGPR cap (cap forced VGPR=32, spilled
//   MFMA accumulators -> +35MB scratch writes). Deadlock-free without full
//   co-residency: only 196 csr blocks spin; min slots = 256 (1 blk/CU x 256 CU);
//   bin/proj blocks retire -> queued blocks always progress.
//   Pipeline: D0 zero+wtrans; D1 mega(bin||proj||csr); D2 agg (R22 unchanged).

#define DIN 256
#define HC 128
#define NH 4
#define NEG 0.2f
#define BCAP 12288
#define LOG2E 1.44269504f

typedef _Float16 half8 __attribute__((ext_vector_type(8)));
typedef _Float16 half2v __attribute__((ext_vector_type(2)));
typedef float f32x4 __attribute__((ext_vector_type(4)));

// ---------------- projection body (MFMA) + fused attention logits ----------------
// Per-sub-block sm layout (18432B): xs [64][40] halves @0; Wl [128][40] @5120;
//   ep [64][136] @0 (reused); attSL @17408, attDL @17920.
// tid = sub-block-local thread id (0..255).
// a_src/a_dst written PRE-SCALED by log2(e) for exp2f consumers.
__device__ __forceinline__ void proj_body(char* sm, int tid, const float* __restrict__ x,
                                          const _Float16* __restrict__ Wt,
                                          const float* __restrict__ attS,
                                          const float* __restrict__ attD,
                                          __half* __restrict__ xph,
                                          float* __restrict__ a_src,
                                          float* __restrict__ a_dst, int n, int node0) {
    _Float16* xs = (_Float16*)sm;
    _Float16* Wl = (_Float16*)(sm + 5120);
    _Float16* ep = (_Float16*)sm;
    float* attSL = (float*)(sm + 17408);
    float* attDL = (float*)(sm + 17920);

    const int wave = tid >> 6;
    const int lane = tid & 63;
    const int l15  = lane & 15;
    const int quad = lane >> 4;

    if (tid < 128) attSL[tid] = attS[tid];
    else           attDL[tid - 128] = attD[tid - 128];

    f32x4 acc[8];
#pragma unroll
    for (int ct = 0; ct < 8; ++ct) acc[ct] = (f32x4){0.f, 0.f, 0.f, 0.f};

    for (int kt = 0; kt < DIN; kt += 32) {
        __syncthreads();
#pragma unroll
        for (int r = 0; r < 4; ++r) {
            int idx = tid + r * 256;
            int row = idx >> 4;
            int kp  = idx & 15;
            int gn = node0 + row;
            float2 xv = make_float2(0.f, 0.f);
            if (gn < n) xv = *(const float2*)&x[(size_t)gn * DIN + kt + kp * 2];
            half2v p; p[0] = (_Float16)xv.x; p[1] = (_Float16)xv.y;
            *(half2v*)&xs[row * 40 + kp * 2] = p;
        }
#pragma unroll
        for (int r = 0; r < 2; ++r) {
            int id = tid + r * 256;
            int c = id >> 2;
            int q = id & 3;
            half8 wv = *(const half8*)&Wt[(size_t)c * 256 + kt + q * 8];
            *(half8*)&Wl[c * 40 + q * 8] = wv;
        }
        __syncthreads();
        half8 af = *(const half8*)&xs[(wave * 16 + l15) * 40 + quad * 8];
#pragma unroll
        for (int ct = 0; ct < 8; ++ct) {
            half8 bf = *(const half8*)&Wl[(ct * 16 + l15) * 40 + quad * 8];
            acc[ct] = __builtin_amdgcn_mfma_f32_16x16x32_f16(af, bf, acc[ct], 0, 0, 0);
        }
    }
    __syncthreads();
#pragma unroll
    for (int ct = 0; ct < 8; ++ct)
#pragma unroll
        for (int r = 0; r < 4; ++r) {
            int row = wave * 16 + quad * 4 + r;
            ep[row * 136 + ct * 16 + l15] = (_Float16)acc[ct][r];
        }
    __syncthreads();
    {
        int row = tid >> 2, ch = tid & 3;
        int node = node0 + row;
        if (node < n) {
            const uint4* s = (const uint4*)&ep[row * 136 + ch * 32];
            uint4* d = (uint4*)&xph[(size_t)node * HC + ch * 32];
            d[0] = s[0]; d[1] = s[1]; d[2] = s[2]; d[3] = s[3];
        }
    }
    {
        int nl = tid >> 2, h = tid & 3;
        int node = node0 + nl;
        if (node < n) {
            float ps = 0.f, pd = 0.f;
            const _Float16* er = &ep[nl * 136 + h * 32];
#pragma unroll
            for (int c = 0; c < 32; ++c) {
                float v = (float)er[c];
                ps += v * attSL[h * 32 + c];
                pd += v * attDL[h * 32 + c];
            }
            a_src[node * NH + h] = ps * LOG2E;
            a_dst[node * NH + h] = pd * LOG2E;
        }
    }
}

// ---------------- D0: zero gcur0+flags || wtrans ----------------
__global__ __launch_bounds__(256) void k_zero_wtrans(int* __restrict__ gz,
                                                     const float* __restrict__ W,
                                                     _Float16* __restrict__ Wt) {
    const int b = blockIdx.x;
    if (b < 2) {
        gz[b * 256 + threadIdx.x] = 0;
    } else {
        int i = (b - 2) * 256 + threadIdx.x;
        int k = i >> 7, c = i & 127;
        Wt[c * 256 + k] = (_Float16)W[i];
    }
}

// ---------------- bin role: one 4096-edge chunk, 512t, self-allocating buckets ----------------
__device__ __forceinline__ void bin_role(char* sm, const int* __restrict__ ei,
                                         int* __restrict__ gcur0,
                                         unsigned* __restrict__ binned,
                                         int e, int n, int chunk) {
    int* h     = (int*)sm;
    int* rbase = (int*)(sm + 1024);
    const int tid = threadIdx.x;
    if (tid < 256) h[tid] = 0;
    __syncthreads();
    const int base = chunk * 4096;
    unsigned pk[8];
    int bk[8];
#pragma unroll
    for (int j = 0; j < 8; ++j) {
        int i = base + j * 512 + tid;
        bk[j] = -1;
        if (i < e) {
            int src = ei[i];
            int dst = ei[e + i];
            if ((unsigned)dst < (unsigned)n && (unsigned)src < (unsigned)n) {
                bk[j] = dst >> 8;
                pk[j] = ((unsigned)(dst & 255) << 16) | (unsigned)src;
                atomicAdd(&h[bk[j]], 1);
            }
        }
    }
    __syncthreads();
    if (tid < 256) {
        if (h[tid]) rbase[tid] = atomicAdd(&gcur0[tid], h[tid]);
        h[tid] = 0;
    }
    __syncthreads();
#pragma unroll
    for (int j = 0; j < 8; ++j) {
        if (bk[j] >= 0) {
            int p = atomicAdd(&h[bk[j]], 1);
            int pib = rbase[bk[j]] + p;
            if (pib < BCAP) binned[(size_t)bk[j] * BCAP + pib] = pk[j];
        }
    }
}

// ---------------- csr role: one bucket counting sort, 512t two-pass ----------------
__device__ __forceinline__ void csr_role(char* sm, const unsigned* __restrict__ binned,
                                         const int* __restrict__ gcnt,
                                         int* __restrict__ off, int* __restrict__ deg,
                                         unsigned short* __restrict__ srt, int n, int b) {
    int* cnt = (int*)sm;
    int* buf = (int*)(sm + 1024);
    int* cur = (int*)(sm + 2048);
    const int tid = threadIdx.x;
    if (tid < 256) { buf[tid] = min(gcnt[tid], BCAP); cnt[tid] = 0; }
    __syncthreads();
    for (int s = 1; s < 256; s <<= 1) {
        int t = (tid < 256 && tid >= s) ? buf[tid - s] : 0;
        __syncthreads();
        if (tid < 256) buf[tid] += t;
        __syncthreads();
    }
    const int cb = min(gcnt[b], BCAP);
    const int excl = buf[b] - cb;                // exclusive scan of counts
    const int pgbase = ((excl + 31) & ~31) + b * 8192;
    const int kb = b * BCAP;
    const int ke = kb + cb;
    __syncthreads();                             // buf reads done before reuse
    for (int i = kb + tid; i < ke; i += 512)
        atomicAdd(&cnt[binned[i] >> 16], 1);
    __syncthreads();
    int v = 0;
    if (tid < 256) { v = cnt[tid]; buf[tid] = (v + 31) & ~31; }
    __syncthreads();
    for (int s = 1; s < 256; s <<= 1) {
        int t = (tid < 256 && tid >= s) ? buf[tid - s] : 0;
        __syncthreads();
        if (tid < 256) buf[tid] += t;
        __syncthreads();
    }
    if (tid < 256) {
        const int myoff = pgbase + buf[tid] - ((v + 31) & ~31);   // 32-aligned
        const int node = b * 256 + tid;
        if (node < n) { off[node] = myoff; deg[node] = v; }
        cur[tid] = myoff;
    }
    __syncthreads();
    for (int i = kb + tid; i < ke; i += 512) {
        unsigned pv = binned[i];
        int nl = pv >> 16;
        int pos = atomicAdd(&cur[nl], 1);
        srt[pos] = (unsigned short)(pv & 0xFFFFu);
    }
}

// ---------------- D1: fused bin || proj || csr (csr waits via RELAXED poll) ----------------
// NO VGPR cap (R24's spill bug). Deadlock-free: only 196 csr blocks spin and
// min slots = 256 (1 blk/CU); bin/proj retire -> queued blocks always progress.
__global__ __launch_bounds__(512) void k_mega(const int* __restrict__ ei,
                                              int* __restrict__ gcur0,
                                              int* __restrict__ flags,
                                              unsigned* __restrict__ binned,
                                              const float* __restrict__ x,
                                              const _Float16* __restrict__ Wt,
                                              const float* __restrict__ attS,
                                              const float* __restrict__ attD,
                                              __half* __restrict__ xph,
                                              float* __restrict__ a_src,
                                              float* __restrict__ a_dst,
                                              int* __restrict__ off,
                                              int* __restrict__ deg,
                                              unsigned short* __restrict__ srt,
                                              int e, int n, int ech, int pbh) {
    __shared__ __attribute__((aligned(16))) char sm[36864];
    const int bid = blockIdx.x;
    const int tid = threadIdx.x;

    if (bid < ech) {
        // ---- bin role; release flags[0] when done ----
        bin_role(sm, ei, gcur0, binned, e, n, bid);
        __threadfence();                            // binned/gcur0 visible device-wide
        __syncthreads();
        if (tid == 0)
            __hip_atomic_fetch_add(&flags[0], 1, __ATOMIC_RELEASE, __HIP_MEMORY_SCOPE_AGENT);
    } else if (bid < ech + pbh) {
        // ---- proj role: fully independent, no polling ----
        const int sub = tid >> 8;                   // 0 or 1
        const int t2  = tid & 255;
        const int tile = (bid - ech) * 2 + sub;
        proj_body(sm + sub * 18432, t2, x, Wt, attS, attD, xph, a_src, a_dst, n, tile * 64);
    } else {
        // ---- csr role: RELAXED poll (no cache ops) until all bins done ----
        if (tid == 0) {
            while (__hip_atomic_load(&flags[0], __ATOMIC_RELAXED, __HIP_MEMORY_SCOPE_AGENT) < ech)
                __builtin_amdgcn_s_sleep(64);
        }
        __syncthreads();
        __threadfence();                            // one acquire-equivalent fence
        csr_role(sm, binned, gcur0, off, deg, srt, n, bid - ech - pbh);
    }
}

// ---------------- D2: aggregate (R22, unchanged) ----------------
__global__ __launch_bounds__(256) void agg_kernel(const __half* __restrict__ xph,
                                                  const float* __restrict__ a_src,
                                                  const float* __restrict__ a_dst,
                                                  const int* __restrict__ off,
                                                  const int* __restrict__ deg,
                                                  const unsigned short* __restrict__ srt,
                                                  const float* __restrict__ bias,
                                                  float* __restrict__ out, int n) {
    int node_ = (blockIdx.x * blockDim.x + threadIdx.x) >> 6;
    if (node_ >= n) return;
    const int node = __builtin_amdgcn_readfirstlane(node_);   // wave-uniform -> SGPR
    const int lane = threadIdx.x & 63;
    const int g = lane >> 4;
    const unsigned l = (unsigned)(lane & 15);
    const unsigned h = l >> 2;
    const unsigned lo8 = l * 8u;

    const float ad = a_dst[((unsigned)node << 2) + h];

    float acc[8];
#pragma unroll
    for (int c = 0; c < 8; ++c) acc[c] = 0.f;
    float den = 0.f;

    if (g == 0) {   // self loop
        float t = a_src[((unsigned)node << 2) + h] + ad;
        float s = exp2f(fmaxf(t, NEG * t));
        half8 xv = *(const half8*)&xph[((unsigned)node << 7) + lo8];
#pragma unroll
        for (int c = 0; c < 8; ++c) acc[c] = s * (float)xv[c];
        den = s;
    }

    const int kb = off[node];
    const int ke = kb + deg[node];
    int k0 = kb;
    for (; k0 + 16 <= ke; k0 += 16) {
        const unsigned kg = (unsigned)(k0 + g * 4);
        const ushort4 s4 = *(const ushort4*)&srt[kg];
        unsigned sv[4] = {s4.x, s4.y, s4.z, s4.w};
        float asv[4];
        half8 hv[4];
#pragma unroll
        for (int j = 0; j < 4; ++j) asv[j] = a_src[(sv[j] << 2) + h];
#pragma unroll
        for (int j = 0; j < 4; ++j)
            hv[j] = *(const half8*)&xph[(sv[j] << 7) + lo8];
#pragma unroll
        for (int j = 0; j < 4; ++j) {
            float t = asv[j] + ad;
            const float s = exp2f(fmaxf(t, NEG * t));
#pragma unroll
            for (int c = 0; c < 8; ++c) acc[c] += s * (float)hv[j][c];
            den += s;
        }
    }
    if (k0 < ke) {   // predicated tail; srt reads stay in padded region
        const unsigned kg = (unsigned)(k0 + g * 4);
        const ushort4 s4 = *(const ushort4*)&srt[kg];
        const unsigned sv[4] = {s4.x, s4.y, s4.z, s4.w};
#pragma unroll
        for (int j = 0; j < 4; ++j) {
            if ((int)kg + j < ke) {
                float t = a_src[(sv[j] << 2) + h] + ad;
                const float s = exp2f(fmaxf(t, NEG * t));
                const half8 hv = *(const half8*)&xph[(sv[j] << 7) + lo8];
#pragma unroll
                for (int c = 0; c < 8; ++c) acc[c] += s * (float)hv[c];
                den += s;
            }
        }
    }

#pragma unroll
    for (int c = 0; c < 8; ++c) acc[c] += __shfl_xor(acc[c], 16, 64);
    den += __shfl_xor(den, 16, 64);
#pragma unroll
    for (int c = 0; c < 8; ++c) acc[c] += __shfl_xor(acc[c], 32, 64);
    den += __shfl_xor(den, 32, 64);

    if (lane < 16) {
        const float inv = 1.0f / den;
        const float4* b4 = (const float4*)&bias[lo8];
        float4 o0, o1;
        o0.x = acc[0] * inv + b4[0].x;
        o0.y = acc[1] * inv + b4[0].y;
        o0.z = acc[2] * inv + b4[0].z;
        o0.w = acc[3] * inv + b4[0].w;
        o1.x = acc[4] * inv + b4[1].x;
        o1.y = acc[5] * inv + b4[1].y;
        o1.z = acc[6] * inv + b4[1].z;
        o1.w = acc[7] * inv + b4[1].w;
        float4* d = (float4*)&out[((unsigned)node << 7) + lo8];
        d[0] = o0;
        d[1] = o1;
    }
}

// ---------------- launch ----------------
extern "C" void kernel_launch(void* const* d_in, const int* in_sizes, int n_in,
                              void* d_out, int out_size, void* d_ws, size_t ws_size,
                              hipStream_t stream) {
    if (n_in < 6 || !d_out || !d_ws) return;
    const float* x    = (const float*)d_in[0];
    const int*   ei   = (const int*)d_in[1];
    const float* W    = (const float*)d_in[2];
    const float* attS = (const float*)d_in[3];
    const float* attD = (const float*)d_in[4];
    const float* bias = (const float*)d_in[5];
    float* out = (float*)d_out;

    const int N = in_sizes[0] / DIN;
    const int E = in_sizes[1] / 2;
    if (N <= 0 || E <= 0) return;
    const int NBUCK = (N + 255) >> 8;
    const int ECH = (E + 4095) / 4096;
    const int PB  = (N + 63) / 64;
    const int PBH = (PB + 1) / 2;
    // guards: 16-bit src packing; 256-bucket scheme; deadlock-free spin needs
    // csr-block count < 256 (min slots = 1 blk/CU x 256 CU)
    if (NBUCK > 255 || N > 65280) return;

    char* ws = (char*)d_ws;
    size_t off_b = 0;
    auto carve = [&](size_t bytes) {
        size_t p = off_b;
        off_b = (off_b + bytes + 255) & ~(size_t)255;
        return (void*)(ws + p);
    };
    __half*         xph    = (__half*)carve((size_t)N * HC * 2);
    _Float16*       Wt     = (_Float16*)carve((size_t)HC * DIN * 2);
    float*          a_src  = (float*)carve((size_t)N * NH * 4);
    float*          a_dst  = (float*)carve((size_t)N * NH * 4);
    int*            gz     = (int*)carve(512 * 4);        // gcur0[256] + flags
    unsigned*       binned = (unsigned*)carve((size_t)NBUCK * BCAP * 4);
    int*            offp   = (int*)carve((size_t)N * 4);
    int*            degp   = (int*)carve((size_t)N * 4);
    unsigned short* srt    = (unsigned short*)carve(((size_t)E + (size_t)NBUCK * 8192 + 64) * 2);
    (void)out_size;
    if (off_b > ws_size) return;

    int* gcur0 = gz;
    int* flags = gz + 256;

    k_zero_wtrans<<<2 + 128, 256, 0, stream>>>(gz, W, Wt);
    k_mega<<<ECH + PBH + NBUCK, 512, 0, stream>>>(ei, gcur0, flags, binned, x, Wt,
                                                  attS, attD, xph, a_src, a_dst,
                                                  offp, degp, srt, E, N, ECH, PBH);
    agg_kernel<<<(N * 64 + 255) / 256, 256, 0, stream>>>(xph, a_src, a_dst,
                                                         offp, degp, srt, bias, out, N);
}